// Round 1
// baseline (131.726 us; speedup 1.0000x reference)
//
#include <hip/hip_runtime.h>

// RoIAlign (aligned-corner variant, divisor = aw-1), fixed problem shape:
//   features: (N=2, C=256, H=200, W=304) f32, rois: (R, 5) f32, scale scalar
//   out: (R, C, 7, 7) f32
#define C_ 256
#define H_ 200
#define W_ 304
#define AH 7
#define AW 7
#define KK (AH * AW)

// ---------- Kernel 1: NCHW -> NHWC transpose into workspace ----------
// Treated per batch as a (C x HW) -> (HW x C) matrix transpose, 64x64 tiles.
// HW = 60800 = 950*64 exactly; C = 256 = 4*64 exactly, so no bounds checks.
__global__ __launch_bounds__(512) void transpose_nchw_nhwc(
    const float* __restrict__ in, float* __restrict__ out) {
    __shared__ float tile[64][65];  // +1 pad: conflict-free both phases
    const int HW = H_ * W_;
    const int n  = blockIdx.z;
    const int p0 = blockIdx.x * 64;  // pixel (h*W+w) tile origin
    const int c0 = blockIdx.y * 64;  // channel tile origin
    const float* inb  = in  + (size_t)n * C_ * HW;
    float*       outb = out + (size_t)n * HW * C_;
    // load: lanes walk pixels (contiguous in NCHW)
    #pragma unroll
    for (int i = threadIdx.y; i < 64; i += 8) {
        tile[i][threadIdx.x] = inb[(size_t)(c0 + i) * HW + (p0 + threadIdx.x)];
    }
    __syncthreads();
    // store: lanes walk channels (contiguous in NHWC)
    #pragma unroll
    for (int i = threadIdx.y; i < 64; i += 8) {
        outb[(size_t)(p0 + i) * C_ + (c0 + threadIdx.x)] = tile[threadIdx.x][i];
    }
}

// ---------- Kernel 2: RoIAlign from NHWC ----------
// One block per ROI. threadIdx.x = channel. 49 sample points, uniform
// addressing per point (scalar regs), 4 coalesced 1KB vector reads per point.
// Stage results in LDS [c][k] (stride 49 -> bank stride 17, conflict-free),
// then write out (R, C, 7, 7) fully coalesced.
__global__ __launch_bounds__(256) void roialign_nhwc(
    const float* __restrict__ tf, const float* __restrict__ rois,
    const float* __restrict__ scale_ptr, float* __restrict__ out) {
    __shared__ float sout[C_ * KK];  // 50176 B
    const int r = blockIdx.x;
    const int c = threadIdx.x;
    const float scale = scale_ptr[0];
    const float* roi = rois + (size_t)r * 5;
    const int   b  = (int)roi[0];
    const float x1 = roi[1] * scale;
    const float y1 = roi[2] * scale;
    const float x2 = roi[3] * scale;
    const float y2 = roi[4] * scale;
    const float roi_w = fmaxf(x2 - x1 + 1.0f, 0.0f);
    const float roi_h = fmaxf(y2 - y1 + 1.0f, 0.0f);
    const float bin_h = roi_h / (float)(AH - 1);
    const float bin_w = roi_w / (float)(AW - 1);
    const float* fb = tf + (size_t)b * H_ * W_ * C_;

    for (int ph = 0; ph < AH; ++ph) {
        const float h  = y1 + (float)ph * bin_h;
        const float hs = fminf(fmaxf(floorf(h), 0.0f), (float)(H_ - 2));
        const float dh = h - hs;
        const int   yi = (int)hs;
        const bool  vh = (h >= 0.0f) && (h < (float)H_);
        #pragma unroll
        for (int pw = 0; pw < AW; ++pw) {
            const float w  = x1 + (float)pw * bin_w;
            const float ws = fminf(fmaxf(floorf(w), 0.0f), (float)(W_ - 2));
            const float dw = w - ws;
            const int   xi = (int)ws;
            const bool  valid = vh && (w >= 0.0f) && (w < (float)W_);
            const float* p = fb + ((size_t)yi * W_ + xi) * C_ + c;
            const float v00 = p[0];
            const float v01 = p[C_];
            const float v10 = p[(size_t)W_ * C_];
            const float v11 = p[(size_t)W_ * C_ + C_];
            float val = v00 * (1.0f - dh) * (1.0f - dw)
                      + v01 * (1.0f - dh) * dw
                      + v10 * dh * (1.0f - dw)
                      + v11 * dh * dw;
            sout[c * KK + ph * AW + pw] = valid ? val : 0.0f;
        }
    }
    __syncthreads();
    float* ob = out + (size_t)r * C_ * KK;
    #pragma unroll 4
    for (int i = threadIdx.x; i < C_ * KK; i += 256) ob[i] = sout[i];
}

// ---------- Fallback: direct NCHW gather (if ws too small) ----------
__global__ __launch_bounds__(256) void roialign_nchw(
    const float* __restrict__ feat, const float* __restrict__ rois,
    const float* __restrict__ scale_ptr, float* __restrict__ out) {
    __shared__ float sout[C_ * KK];
    const int r = blockIdx.x;
    const int c = threadIdx.x;
    const float scale = scale_ptr[0];
    const float* roi = rois + (size_t)r * 5;
    const int   b  = (int)roi[0];
    const float x1 = roi[1] * scale;
    const float y1 = roi[2] * scale;
    const float x2 = roi[3] * scale;
    const float y2 = roi[4] * scale;
    const float roi_w = fmaxf(x2 - x1 + 1.0f, 0.0f);
    const float roi_h = fmaxf(y2 - y1 + 1.0f, 0.0f);
    const float bin_h = roi_h / (float)(AH - 1);
    const float bin_w = roi_w / (float)(AW - 1);
    const float* fb = feat + ((size_t)b * C_ + c) * (H_ * W_);

    for (int ph = 0; ph < AH; ++ph) {
        const float h  = y1 + (float)ph * bin_h;
        const float hs = fminf(fmaxf(floorf(h), 0.0f), (float)(H_ - 2));
        const float dh = h - hs;
        const int   yi = (int)hs;
        const bool  vh = (h >= 0.0f) && (h < (float)H_);
        #pragma unroll
        for (int pw = 0; pw < AW; ++pw) {
            const float w  = x1 + (float)pw * bin_w;
            const float ws = fminf(fmaxf(floorf(w), 0.0f), (float)(W_ - 2));
            const float dw = w - ws;
            const int   xi = (int)ws;
            const bool  valid = vh && (w >= 0.0f) && (w < (float)W_);
            const float v00 = fb[(size_t)yi * W_ + xi];
            const float v01 = fb[(size_t)yi * W_ + xi + 1];
            const float v10 = fb[(size_t)(yi + 1) * W_ + xi];
            const float v11 = fb[(size_t)(yi + 1) * W_ + xi + 1];
            float val = v00 * (1.0f - dh) * (1.0f - dw)
                      + v01 * (1.0f - dh) * dw
                      + v10 * dh * (1.0f - dw)
                      + v11 * dh * dw;
            sout[c * KK + ph * AW + pw] = valid ? val : 0.0f;
        }
    }
    __syncthreads();
    float* ob = out + (size_t)r * C_ * KK;
    #pragma unroll 4
    for (int i = threadIdx.x; i < C_ * KK; i += 256) ob[i] = sout[i];
}

extern "C" void kernel_launch(void* const* d_in, const int* in_sizes, int n_in,
                              void* d_out, int out_size, void* d_ws, size_t ws_size,
                              hipStream_t stream) {
    const float* feat  = (const float*)d_in[0];
    const float* rois  = (const float*)d_in[1];
    const float* scale = (const float*)d_in[2];
    float* out = (float*)d_out;

    const int R = in_sizes[1] / 5;                 // 2000
    const int N = in_sizes[0] / (C_ * H_ * W_);    // 2
    const size_t need = (size_t)N * C_ * H_ * W_ * sizeof(float);

    if (ws_size >= need) {
        float* tf = (float*)d_ws;
        dim3 tb(64, 8);
        dim3 tg((H_ * W_) / 64, C_ / 64, N);       // 950 x 4 x 2
        hipLaunchKernelGGL(transpose_nchw_nhwc, tg, tb, 0, stream, feat, tf);
        hipLaunchKernelGGL(roialign_nhwc, dim3(R), dim3(256), 0, stream,
                           tf, rois, scale, out);
    } else {
        hipLaunchKernelGGL(roialign_nchw, dim3(R), dim3(256), 0, stream,
                           feat, rois, scale, out);
    }
}

// Round 2
// 78.995 us; speedup vs baseline: 1.6675x; 1.6675x over previous
//
#include <hip/hip_runtime.h>

// RoIAlign (aligned-corner variant), fixed shape:
//   features: (N=2, C=256, H=200, W=304) f32 NCHW, rois: (R,5) f32, scale f32
//   out: (R, 256, 7, 7) f32
// Pipeline: NCHW f32 -> NHWC bf16 transpose (ws), then coalesced gather.
#define C_ 256
#define H_ 200
#define W_ 304
#define AH 7
#define AW 7
#define KK (AH * AW)
#define SP 260  // sout row pad (words): 16B-aligned rows, conflict-free b128 writes

__device__ __forceinline__ unsigned short bf16_rn(float f) {
    unsigned int u = __float_as_uint(f);
    unsigned int r = (u + 0x7FFFu + ((u >> 16) & 1u)) >> 16;
    return (unsigned short)r;
}
__device__ __forceinline__ float b2f(unsigned short s) {
    return __uint_as_float((unsigned int)s << 16);
}

// ---------- Kernel 1: NCHW f32 -> NHWC bf16 ----------
// Tile: 64 pixels x 128 channels. float4 loads along pixels, ushort4 stores
// along channels. LDS tile[128][65] f32 (pad: 2-way write / 4-way read).
__global__ __launch_bounds__(256) void transpose_nchw_nhwc_bf16(
    const float* __restrict__ in, unsigned short* __restrict__ out) {
    __shared__ float tile[128][65];  // 33280 B
    const int HW = H_ * W_;
    const int n  = blockIdx.z;
    const int p0 = blockIdx.x * 64;   // pixel tile origin
    const int c0 = blockIdx.y * 128;  // channel tile origin
    const float* inb = in + (size_t)n * C_ * HW;
    unsigned short* outb = out + (size_t)n * HW * C_;

    // load: lanes walk pixel-quads (float4, contiguous in NCHW)
    {
        const int q  = threadIdx.x & 15;   // pixel quad 0..15
        const int r0 = threadIdx.x >> 4;   // 0..15
        #pragma unroll
        for (int i = 0; i < 8; ++i) {
            const int c = r0 + 16 * i;     // 0..127
            const float4 v = *(const float4*)&inb[(size_t)(c0 + c) * HW + p0 + 4 * q];
            tile[c][4 * q + 0] = v.x;
            tile[c][4 * q + 1] = v.y;
            tile[c][4 * q + 2] = v.z;
            tile[c][4 * q + 3] = v.w;
        }
    }
    __syncthreads();
    // store: lanes walk channel-quads (ushort4, contiguous in NHWC)
    {
        const int cq = threadIdx.x & 31;   // channel quad 0..31
        const int pr = threadIdx.x >> 5;   // 0..7
        #pragma unroll
        for (int i = 0; i < 8; ++i) {
            const int p = pr + 8 * i;      // 0..63
            ushort4 o;
            o.x = bf16_rn(tile[4 * cq + 0][p]);
            o.y = bf16_rn(tile[4 * cq + 1][p]);
            o.z = bf16_rn(tile[4 * cq + 2][p]);
            o.w = bf16_rn(tile[4 * cq + 3][p]);
            *(ushort4*)&outb[(size_t)(p0 + p) * C_ + c0 + 4 * cq] = o;
        }
    }
}

// ---------- Kernel 2: RoIAlign gather from NHWC bf16 ----------
// One block (256 thr = 4 waves) per ROI. Wave w handles points k = w, w+4, ...
// Lane owns 4 channels (ushort4 = 8B corner loads). Stage f32 results in
// LDS [49][SP], then coalesced copy to (R, C, 7, 7).
__global__ __launch_bounds__(256) void roialign_nhwc_bf16(
    const unsigned short* __restrict__ tf, const float* __restrict__ rois,
    const float* __restrict__ scale_ptr, float* __restrict__ out) {
    __shared__ float sout[KK * SP];  // 50960 B
    const int r    = blockIdx.x;
    const int wave = threadIdx.x >> 6;
    const int lane = threadIdx.x & 63;
    const int c4   = lane * 4;

    const float scale = scale_ptr[0];
    const float* roi = rois + (size_t)r * 5;
    const int   b  = (int)roi[0];
    const float x1 = roi[1] * scale;
    const float y1 = roi[2] * scale;
    const float x2 = roi[3] * scale;
    const float y2 = roi[4] * scale;
    const float roi_w = fmaxf(x2 - x1 + 1.0f, 0.0f);
    const float roi_h = fmaxf(y2 - y1 + 1.0f, 0.0f);
    const float bin_h = roi_h / (float)(AH - 1);
    const float bin_w = roi_w / (float)(AW - 1);
    const unsigned short* fb = tf + (size_t)b * (H_ * W_) * C_;

    for (int k = wave; k < KK; k += 4) {
        const int ph = k / AW;
        const int pw = k - ph * AW;
        const float h  = y1 + (float)ph * bin_h;
        const float w  = x1 + (float)pw * bin_w;
        const float hs = fminf(fmaxf(floorf(h), 0.0f), (float)(H_ - 2));
        const float ws = fminf(fmaxf(floorf(w), 0.0f), (float)(W_ - 2));
        const float dh = h - hs;
        const float dw = w - ws;
        const int   yi = (int)hs;
        const int   xi = (int)ws;
        const bool  valid = (h >= 0.0f) && (h < (float)H_) &&
                            (w >= 0.0f) && (w < (float)W_);
        const unsigned short* p = fb + ((size_t)yi * W_ + xi) * C_ + c4;
        const ushort4 a00 = *(const ushort4*)p;
        const ushort4 a01 = *(const ushort4*)(p + C_);
        const ushort4 a10 = *(const ushort4*)(p + (size_t)W_ * C_);
        const ushort4 a11 = *(const ushort4*)(p + (size_t)W_ * C_ + C_);
        const float w00 = (1.0f - dh) * (1.0f - dw);
        const float w01 = (1.0f - dh) * dw;
        const float w10 = dh * (1.0f - dw);
        const float w11 = dh * dw;
        float4 v;
        v.x = b2f(a00.x) * w00 + b2f(a01.x) * w01 + b2f(a10.x) * w10 + b2f(a11.x) * w11;
        v.y = b2f(a00.y) * w00 + b2f(a01.y) * w01 + b2f(a10.y) * w10 + b2f(a11.y) * w11;
        v.z = b2f(a00.z) * w00 + b2f(a01.z) * w01 + b2f(a10.z) * w10 + b2f(a11.z) * w11;
        v.w = b2f(a00.w) * w00 + b2f(a01.w) * w01 + b2f(a10.w) * w10 + b2f(a11.w) * w11;
        if (!valid) { v.x = 0.0f; v.y = 0.0f; v.z = 0.0f; v.w = 0.0f; }
        *(float4*)&sout[k * SP + c4] = v;
    }
    __syncthreads();
    float* ob = out + (size_t)r * C_ * KK;
    for (int i = threadIdx.x; i < C_ * KK; i += 256) {
        const int c = i / KK;
        const int k = i - c * KK;
        ob[i] = sout[k * SP + c];
    }
}

// ---------- Fallback: direct NCHW gather (if ws too small) ----------
__global__ __launch_bounds__(256) void roialign_nchw(
    const float* __restrict__ feat, const float* __restrict__ rois,
    const float* __restrict__ scale_ptr, float* __restrict__ out) {
    __shared__ float sout[C_ * KK];
    const int r = blockIdx.x;
    const int c = threadIdx.x;
    const float scale = scale_ptr[0];
    const float* roi = rois + (size_t)r * 5;
    const int   b  = (int)roi[0];
    const float x1 = roi[1] * scale;
    const float y1 = roi[2] * scale;
    const float x2 = roi[3] * scale;
    const float y2 = roi[4] * scale;
    const float roi_w = fmaxf(x2 - x1 + 1.0f, 0.0f);
    const float roi_h = fmaxf(y2 - y1 + 1.0f, 0.0f);
    const float bin_h = roi_h / (float)(AH - 1);
    const float bin_w = roi_w / (float)(AW - 1);
    const float* fb = feat + ((size_t)b * C_ + c) * (H_ * W_);

    for (int ph = 0; ph < AH; ++ph) {
        const float h  = y1 + (float)ph * bin_h;
        const float hs = fminf(fmaxf(floorf(h), 0.0f), (float)(H_ - 2));
        const float dh = h - hs;
        const int   yi = (int)hs;
        const bool  vh = (h >= 0.0f) && (h < (float)H_);
        #pragma unroll
        for (int pw = 0; pw < AW; ++pw) {
            const float w  = x1 + (float)pw * bin_w;
            const float ws = fminf(fmaxf(floorf(w), 0.0f), (float)(W_ - 2));
            const float dw = w - ws;
            const int   xi = (int)ws;
            const bool  valid = vh && (w >= 0.0f) && (w < (float)W_);
            const float v00 = fb[(size_t)yi * W_ + xi];
            const float v01 = fb[(size_t)yi * W_ + xi + 1];
            const float v10 = fb[(size_t)(yi + 1) * W_ + xi];
            const float v11 = fb[(size_t)(yi + 1) * W_ + xi + 1];
            float val = v00 * (1.0f - dh) * (1.0f - dw)
                      + v01 * (1.0f - dh) * dw
                      + v10 * dh * (1.0f - dw)
                      + v11 * dh * dw;
            sout[c * KK + ph * AW + pw] = valid ? val : 0.0f;
        }
    }
    __syncthreads();
    float* ob = out + (size_t)r * C_ * KK;
    #pragma unroll 4
    for (int i = threadIdx.x; i < C_ * KK; i += 256) ob[i] = sout[i];
}

extern "C" void kernel_launch(void* const* d_in, const int* in_sizes, int n_in,
                              void* d_out, int out_size, void* d_ws, size_t ws_size,
                              hipStream_t stream) {
    const float* feat  = (const float*)d_in[0];
    const float* rois  = (const float*)d_in[1];
    const float* scale = (const float*)d_in[2];
    float* out = (float*)d_out;

    const int R = in_sizes[1] / 5;                 // 2000
    const int N = in_sizes[0] / (C_ * H_ * W_);    // 2
    const size_t need = (size_t)N * C_ * H_ * W_ * sizeof(unsigned short);

    if (ws_size >= need) {
        unsigned short* tf = (unsigned short*)d_ws;
        dim3 tb(256);
        dim3 tg((H_ * W_) / 64, C_ / 128, N);      // 950 x 2 x 2
        hipLaunchKernelGGL(transpose_nchw_nhwc_bf16, tg, tb, 0, stream, feat, tf);
        hipLaunchKernelGGL(roialign_nhwc_bf16, dim3(R), dim3(256), 0, stream,
                           tf, rois, scale, out);
    } else {
        hipLaunchKernelGGL(roialign_nchw, dim3(R), dim3(256), 0, stream,
                           feat, rois, scale, out);
    }
}